// Round 1
// baseline (2237.188 us; speedup 1.0000x reference)
//
#include <hip/hip_runtime.h>
#include <math.h>

// ---------------------------------------------------------------------------
// Full U-Mamba block, fp32.
// Shapes: x [2,64,32,32,32]; conv 64->64 k=3 p=1; mamba: 2048 seqs x l=32,
// C=64, d_inner=128, d_state=16, d_conv=4.
// ---------------------------------------------------------------------------

__device__ __forceinline__ float siluf(float x){ return x * (1.0f / (1.0f + __expf(-x))); }
__device__ __forceinline__ float softplusf(float x){ return fmaxf(x, 0.0f) + log1pf(__expf(-fabsf(x))); }

// ---------------------------------------------------------------------------
// Conv3d(k=3, pad=1), 64->64 channels + bias. Tile: 4(h) x 8(w) x 32(d) out,
// halo tile 6x10x34 per input channel in LDS. 4 outputs per thread along d.
// grid (32 tiles, 64 c_out, 2 batch), block 256.
// ---------------------------------------------------------------------------
__global__ __launch_bounds__(256) void conv3d_k(const float* __restrict__ x,
    const float* __restrict__ wt, const float* __restrict__ bias, float* __restrict__ y)
{
  __shared__ float tile[6][10][34];
  const int t  = threadIdx.x;
  const int co = blockIdx.y, b = blockIdx.z;
  const int th = blockIdx.x >> 2, tw = blockIdx.x & 3;
  const int h0 = th * 4, w0 = tw * 8;
  const int d0 = (t & 7) * 4;
  const int wl = (t >> 3) & 7;
  const int hl = t >> 6;
  const float bv = bias[co];
  float acc0 = bv, acc1 = bv, acc2 = bv, acc3 = bv;
  const float* xb = x + (size_t)b * 2097152;

  for (int ci = 0; ci < 64; ci++){
    __syncthreads();
    for (int f = t; f < 2040; f += 256){           // 6*10*34 floats
      int hh = f / 340; int rem = f - hh * 340;
      int ww = rem / 34; int dd = rem - ww * 34;
      int h = h0 - 1 + hh, w = w0 - 1 + ww, d = dd - 1;
      float v = 0.0f;
      if (h >= 0 && h < 32 && w >= 0 && w < 32 && d >= 0 && d < 32)
        v = xb[ci * 32768 + h * 1024 + w * 32 + d];
      tile[hh][ww][dd] = v;
    }
    __syncthreads();
    const float* wp = wt + (co * 64 + ci) * 27;    // block-uniform -> s_load
    #pragma unroll
    for (int i = 0; i < 3; i++){
      #pragma unroll
      for (int j = 0; j < 3; j++){
        const float* r = &tile[hl + i][wl + j][d0];
        float v0 = r[0], v1 = r[1], v2 = r[2], v3 = r[3], v4 = r[4], v5 = r[5];
        float k0 = wp[(i*3 + j)*3 + 0], k1 = wp[(i*3 + j)*3 + 1], k2 = wp[(i*3 + j)*3 + 2];
        acc0 += k0*v0 + k1*v1 + k2*v2;
        acc1 += k0*v1 + k1*v2 + k2*v3;
        acc2 += k0*v2 + k1*v3 + k2*v4;
        acc3 += k0*v3 + k1*v4 + k2*v5;
      }
    }
  }
  size_t idx = ((size_t)(b * 64 + co) << 15) + (size_t)(h0 + hl) * 1024 + (w0 + wl) * 32 + d0;
  float4 o; o.x = acc0; o.y = acc1; o.z = acc2; o.w = acc3;
  *(float4*)&y[idx] = o;
}

// ---------------------------------------------------------------------------
// InstanceNorm3d stats: one block per (b,c) group of 32768 elements.
// stats[0..127]=mu, stats[128..255]=rsigma
// ---------------------------------------------------------------------------
__global__ __launch_bounds__(256) void inorm_stats_k(const float* __restrict__ y,
                                                     float* __restrict__ stats)
{
  __shared__ float ss[256], ss2[256];
  const int t = threadIdx.x, g = blockIdx.x;
  const float* p = y + (size_t)g * 32768;
  float s = 0.0f, s2 = 0.0f;
  for (int i = t; i < 32768; i += 256){ float v = p[i]; s += v; s2 += v * v; }
  ss[t] = s; ss2[t] = s2;
  __syncthreads();
  for (int off = 128; off > 0; off >>= 1){
    if (t < off){ ss[t] += ss[t + off]; ss2[t] += ss2[t + off]; }
    __syncthreads();
  }
  if (t == 0){
    float mu = ss[0] * (1.0f / 32768.0f);
    float var = ss2[0] * (1.0f / 32768.0f) - mu * mu;
    stats[g] = mu;
    stats[128 + g] = rsqrtf(var + 1e-5f);
  }
}

// normalize + LeakyReLU(0.01) + residual add
__global__ __launch_bounds__(256) void inorm_apply_k(const float* __restrict__ xin,
    const float* __restrict__ y, const float* __restrict__ stats, float* __restrict__ xout)
{
  int i = blockIdx.x * 256 + threadIdx.x;
  int g = i >> 15;
  float v = (y[i] - stats[g]) * stats[128 + g];
  v = (v >= 0.0f) ? v : 0.01f * v;
  xout[i] = xin[i] + v;
}

// ---------------------------------------------------------------------------
// Pre-transpose projection weights so per-lane reads are coalesced.
// Layout in T: lT[64][128]@0, rT[64][128]@8192, dT[128][128]@16384,
//              bT[128][16]@32768, cT[128][16]@34816, oT[128][64]@36864
// ---------------------------------------------------------------------------
__global__ __launch_bounds__(256) void transpose_weights_k(
    const float* __restrict__ lw, const float* __restrict__ rw, const float* __restrict__ dw,
    const float* __restrict__ bw, const float* __restrict__ cw, const float* __restrict__ ow,
    float* __restrict__ T)
{
  int i = blockIdx.x * 256 + threadIdx.x;   // 45056 total
  if (i < 8192){ int c = i >> 7, dd = i & 127; T[i] = lw[dd * 64 + c]; }
  else if (i < 16384){ int j = i - 8192;  int c = j >> 7, dd = j & 127; T[i] = rw[dd * 64 + c]; }
  else if (i < 32768){ int j = i - 16384; int k = j >> 7, dd = j & 127; T[i] = dw[dd * 128 + k]; }
  else if (i < 34816){ int j = i - 32768; int dd = j >> 4, s = j & 15;  T[i] = bw[s * 128 + dd]; }
  else if (i < 36864){ int j = i - 34816; int dd = j >> 4, s = j & 15;  T[i] = cw[s * 128 + dd]; }
  else if (i < 45056){ int j = i - 36864; int dd = j >> 6, c = j & 63;  T[i] = ow[c * 128 + dd]; }
}

// ---------------------------------------------------------------------------
// One block per sequence (n = 2048), 256 threads.
// LDS activations stored transposed [feature][l], stride 36 (16B-aligned rows
// -> ds_read_b128 broadcast in the projection k-loops).
// s_a uses stride 33 (scalar access only, conflict-free).
// B/C [32][16] matrices live in the 4-float padding holes of s_y / s_xl.
// Total LDS: 63,232 B -> 2 blocks/CU.
// ---------------------------------------------------------------------------
__global__ __launch_bounds__(256) void mamba_k(
    const float* __restrict__ x2, const float* __restrict__ ln_w, const float* __restrict__ ln_b,
    const float* __restrict__ Twt, const float* __restrict__ cw, const float* __restrict__ cb,
    const float* __restrict__ db, const float* __restrict__ alog,
    const float* __restrict__ pnw, const float* __restrict__ pnb,
    const float* __restrict__ axw, float* __restrict__ accum, int axis, int first)
{
  __shared__ __align__(16) float smem[15808];
  float* s_ln = smem;            // [64][36]  raw x -> ln(x)
  float* s_a  = smem + 2304;     // [128][33] raw left proj -> delta
  float* s_xl = smem + 6528;     // [128][36] conv1d+silu out; holes: C; rows<64 reused for out
  float* s_y  = smem + 11136;    // [128][36] scan out -> gated -> pn; holes: B
  float* s_mu = smem + 15744;    // [32]
  float* s_rs = smem + 15776;    // [32]

  const float* lT = Twt;
  const float* rT = Twt + 8192;
  const float* dT = Twt + 16384;
  const float* bT = Twt + 32768;
  const float* cT = Twt + 34816;
  const float* oT = Twt + 36864;

  const int t = threadIdx.x;
  const int n = blockIdx.x;
  const int b = n >> 10, r1 = (n >> 5) & 31, r0 = n & 31;
  size_t base; int lstride;
  if (axis == 0){      base = ((size_t)b << 21) + (r1 << 5)  + r0;        lstride = 1024; } // h=l,w=r1,d=r0
  else if (axis == 1){ base = ((size_t)b << 21) + (r1 << 10) + r0;        lstride = 32;   } // h=r1,w=l,d=r0
  else {               base = ((size_t)b << 21) + (r1 << 10) + (r0 << 5); lstride = 1;    } // h=r1,w=r0,d=l

  // 1. gather sequence into s_ln (transposed [c][l])
  for (int i = t; i < 2048; i += 256){
    int c = i >> 5, l = i & 31;
    s_ln[c * 36 + l] = x2[base + (size_t)c * 32768 + (size_t)l * lstride];
  }
  __syncthreads();

  // 2. layernorm stats over C per position
  if (t < 32){
    float s = 0.0f, s2 = 0.0f;
    for (int c = 0; c < 64; c++){ float v = s_ln[c * 36 + t]; s += v; s2 += v * v; }
    float mu = s * (1.0f / 64.0f);
    float var = s2 * (1.0f / 64.0f) - mu * mu;
    s_mu[t] = mu; s_rs[t] = rsqrtf(var + 1e-5f);
  }
  __syncthreads();

  // 3. apply layernorm in place
  for (int i = t; i < 2048; i += 256){
    int c = i >> 5, l = i & 31;
    s_ln[c * 36 + l] = (s_ln[c * 36 + l] - s_mu[l]) * s_rs[l] * ln_w[c] + ln_b[c];
  }
  __syncthreads();

  // 4. left projection: [32,64] @ [64,128]^T -> s_a[dd][l]
  {
    const int dd = t & 127, l0 = (t >> 7) * 16;
    float acc[16];
    #pragma unroll
    for (int j = 0; j < 16; j++) acc[j] = 0.0f;
    #pragma unroll 4
    for (int c = 0; c < 64; c++){
      float wv = lT[c * 128 + dd];
      #pragma unroll
      for (int q = 0; q < 4; q++){
        float4 xv = *(const float4*)&s_ln[c * 36 + l0 + q * 4];
        acc[q*4+0] += wv * xv.x; acc[q*4+1] += wv * xv.y;
        acc[q*4+2] += wv * xv.z; acc[q*4+3] += wv * xv.w;
      }
    }
    #pragma unroll
    for (int j = 0; j < 16; j++) s_a[dd * 33 + l0 + j] = acc[j];
  }
  __syncthreads();

  // 5. causal depthwise conv1d (k=4) + bias + silu -> s_xl[dd][l]
  {
    const int dd = t & 127, l0 = (t >> 7) * 16;
    float4 cwv = *(const float4*)&cw[dd * 4];
    float bb = cb[dd];
    float vm3, vm2, vm1;
    if (l0 == 0){ vm3 = vm2 = vm1 = 0.0f; }
    else { vm3 = s_a[dd*33 + l0 - 3]; vm2 = s_a[dd*33 + l0 - 2]; vm1 = s_a[dd*33 + l0 - 1]; }
    #pragma unroll
    for (int j = 0; j < 16; j++){
      float cur = s_a[dd * 33 + l0 + j];
      float v = bb + cwv.x * vm3 + cwv.y * vm2 + cwv.z * vm1 + cwv.w * cur;
      s_xl[dd * 36 + l0 + j] = siluf(v);
      vm3 = vm2; vm2 = vm1; vm1 = cur;
    }
  }
  __syncthreads();

  // 6a. delta projection: softplus(xl @ delta_w^T + db), clip -> s_a[dd][l]
  {
    const int dd = t & 127, l0 = (t >> 7) * 16;
    float acc[16];
    #pragma unroll
    for (int j = 0; j < 16; j++) acc[j] = 0.0f;
    #pragma unroll 4
    for (int k = 0; k < 128; k++){
      float wv = dT[k * 128 + dd];
      #pragma unroll
      for (int q = 0; q < 4; q++){
        float4 xv = *(const float4*)&s_xl[k * 36 + l0 + q * 4];
        acc[q*4+0] += wv * xv.x; acc[q*4+1] += wv * xv.y;
        acc[q*4+2] += wv * xv.z; acc[q*4+3] += wv * xv.w;
      }
    }
    float bb = db[dd];
    #pragma unroll
    for (int j = 0; j < 16; j++){
      float z = softplusf(acc[j] + bb);
      s_a[dd * 33 + l0 + j] = fminf(fmaxf(z, 1e-4f), 10.0f);
    }
  }
  // 6b. B/C projections into padding holes of s_y / s_xl (disjoint addresses)
  {
    const int s = t & 15, which = (t >> 4) & 1, lg = t >> 5;
    const int l0 = lg * 4;
    const float* W = which ? cT : bT;
    float acc4[4] = {0.0f, 0.0f, 0.0f, 0.0f};
    #pragma unroll 4
    for (int k = 0; k < 128; k++){
      float wv = W[k * 16 + s];
      float4 xv = *(const float4*)&s_xl[k * 36 + l0];
      acc4[0] += wv * xv.x; acc4[1] += wv * xv.y; acc4[2] += wv * xv.z; acc4[3] += wv * xv.w;
    }
    float* H = which ? s_xl : s_y;
    #pragma unroll
    for (int j = 0; j < 4; j++){
      int ib = (l0 + j) * 16 + s;
      H[(ib >> 2) * 36 + 32 + (ib & 3)] = acc4[j];
    }
  }
  __syncthreads();

  // 7. selective scan: thread dd (t<128) owns h[16] in registers
  if (t < 128){
    float A[16], h[16];
    #pragma unroll
    for (int s = 0; s < 16; s++){ A[s] = -softplusf(alog[s]); h[s] = 0.0f; }
    const int dd = t;
    for (int l = 0; l < 32; l++){
      float dt = s_a[dd * 33 + l];
      float xt = s_xl[dd * 36 + l];
      float dx = dt * xt;
      float yv = 0.0f;
      #pragma unroll
      for (int s = 0; s < 16; s++){
        int ib = l * 16 + s;
        float Bv = s_y[(ib >> 2) * 36 + 32 + (ib & 3)];
        float Cv = s_xl[(ib >> 2) * 36 + 32 + (ib & 3)];
        h[s] = __expf(dt * A[s]) * h[s] + dx * Bv;
        yv += h[s] * Cv;
      }
      s_y[dd * 36 + l] = yv;
    }
  }
  __syncthreads();

  // 8. gate: y *= silu(ln_x @ right_w^T)
  {
    const int dd = t & 127, l0 = (t >> 7) * 16;
    float acc[16];
    #pragma unroll
    for (int j = 0; j < 16; j++) acc[j] = 0.0f;
    #pragma unroll 4
    for (int c = 0; c < 64; c++){
      float wv = rT[c * 128 + dd];
      #pragma unroll
      for (int q = 0; q < 4; q++){
        float4 xv = *(const float4*)&s_ln[c * 36 + l0 + q * 4];
        acc[q*4+0] += wv * xv.x; acc[q*4+1] += wv * xv.y;
        acc[q*4+2] += wv * xv.z; acc[q*4+3] += wv * xv.w;
      }
    }
    #pragma unroll
    for (int j = 0; j < 16; j++) s_y[dd * 36 + l0 + j] *= siluf(acc[j]);
  }
  __syncthreads();

  // 9. post-norm stats over d_inner=128 per position
  if (t < 32){
    float s = 0.0f, s2 = 0.0f;
    for (int k = 0; k < 128; k++){ float v = s_y[k * 36 + t]; s += v; s2 += v * v; }
    float mu = s * (1.0f / 128.0f);
    float var = s2 * (1.0f / 128.0f) - mu * mu;
    s_mu[t] = mu; s_rs[t] = rsqrtf(var + 1e-5f);
  }
  __syncthreads();

  // 10. apply post-norm
  for (int i = t; i < 4096; i += 256){
    int dd = i >> 5, l = i & 31;
    s_y[dd * 36 + l] = (s_y[dd * 36 + l] - s_mu[l]) * s_rs[l] * pnw[dd] + pnb[dd];
  }
  __syncthreads();

  // 11. out projection [32,128] @ [128,64]^T -> stage into s_xl rows 0..63
  {
    const int c = t & 63, lg = t >> 6, l0 = lg * 8;
    float acc[8];
    #pragma unroll
    for (int j = 0; j < 8; j++) acc[j] = 0.0f;
    #pragma unroll 4
    for (int k = 0; k < 128; k++){
      float wv = oT[k * 64 + c];
      float4 a  = *(const float4*)&s_y[k * 36 + l0];
      float4 b4 = *(const float4*)&s_y[k * 36 + l0 + 4];
      acc[0] += wv * a.x;  acc[1] += wv * a.y;  acc[2] += wv * a.z;  acc[3] += wv * a.w;
      acc[4] += wv * b4.x; acc[5] += wv * b4.y; acc[6] += wv * b4.z; acc[7] += wv * b4.w;
    }
    #pragma unroll
    for (int j = 0; j < 8; j++) s_xl[c * 36 + l0 + j] = acc[j];
  }
  __syncthreads();

  // 12. weighted scatter to accumulation buffer (d_out)
  float a0 = axw[0], a1 = axw[1], a2 = axw[2];
  float mx = fmaxf(a0, fmaxf(a1, a2));
  float e0 = __expf(a0 - mx), e1 = __expf(a1 - mx), e2 = __expf(a2 - mx);
  float wax = ((axis == 0) ? e0 : (axis == 1) ? e1 : e2) / (e0 + e1 + e2);
  for (int i = t; i < 2048; i += 256){
    int c = i >> 5, l = i & 31;
    float v = wax * s_xl[c * 36 + l];
    size_t idx = base + (size_t)c * 32768 + (size_t)l * lstride;
    if (first) accum[idx] = v;
    else       accum[idx] += v;
  }
}

// out = identity + res_scale * accum  (in-place on d_out)
__global__ __launch_bounds__(256) void final_k(const float* __restrict__ x,
    const float* __restrict__ rs, float* __restrict__ out)
{
  int i = blockIdx.x * 256 + threadIdx.x;
  out[i] = x[i] + rs[0] * out[i];
}

// ---------------------------------------------------------------------------
extern "C" void kernel_launch(void* const* d_in, const int* in_sizes, int n_in,
                              void* d_out, int out_size, void* d_ws, size_t ws_size,
                              hipStream_t stream)
{
  const float* x      = (const float*)d_in[0];
  const float* cr1w   = (const float*)d_in[1];
  const float* cr1b   = (const float*)d_in[2];
  const float* cr2w   = (const float*)d_in[3];
  const float* cr2b   = (const float*)d_in[4];
  const float* ln_w   = (const float*)d_in[5];
  const float* ln_b   = (const float*)d_in[6];
  const float* left_w = (const float*)d_in[7];
  const float* c1dw   = (const float*)d_in[8];
  const float* c1db   = (const float*)d_in[9];
  const float* dw     = (const float*)d_in[10];
  const float* db     = (const float*)d_in[11];
  const float* bpw    = (const float*)d_in[12];
  const float* cpw    = (const float*)d_in[13];
  const float* alog   = (const float*)d_in[14];
  const float* rw     = (const float*)d_in[15];
  const float* pnw    = (const float*)d_in[16];
  const float* pnb    = (const float*)d_in[17];
  const float* ow     = (const float*)d_in[18];
  const float* rsc    = (const float*)d_in[19];
  const float* axw    = (const float*)d_in[20];
  float* out  = (float*)d_out;
  float* wsf  = (float*)d_ws;
  float* buf0  = wsf;                    // 4,194,304 floats: conv raw out
  float* buf1  = wsf + 4194304;          // 4,194,304 floats: x1 -> x2
  float* stats = wsf + 8388608;          // 256 floats
  float* Twt   = wsf + 8388608 + 256;    // 45,056 floats transposed weights

  transpose_weights_k<<<176, 256, 0, stream>>>(left_w, rw, dw, bpw, cpw, ow, Twt);

  dim3 cgrid(32, 64, 2);
  // conv-res block 1
  conv3d_k<<<cgrid, 256, 0, stream>>>(x, cr1w, cr1b, buf0);
  inorm_stats_k<<<128, 256, 0, stream>>>(buf0, stats);
  inorm_apply_k<<<16384, 256, 0, stream>>>(x, buf0, stats, buf1);
  // conv-res block 2 (x2 written in place over x1)
  conv3d_k<<<cgrid, 256, 0, stream>>>(buf1, cr2w, cr2b, buf0);
  inorm_stats_k<<<128, 256, 0, stream>>>(buf0, stats);
  inorm_apply_k<<<16384, 256, 0, stream>>>(buf1, buf0, stats, buf1);
  // three axis-wise mamba passes, accumulate into d_out
  for (int axis = 0; axis < 3; axis++)
    mamba_k<<<2048, 256, 0, stream>>>(buf1, ln_w, ln_b, Twt, c1dw, c1db, db, alog,
                                      pnw, pnb, axw, out, axis, axis == 0 ? 1 : 0);
  // residual combine
  final_k<<<16384, 256, 0, stream>>>(x, rsc, out);
}

// Round 2
// 1252.723 us; speedup vs baseline: 1.7859x; 1.7859x over previous
//
#include <hip/hip_runtime.h>
#include <hip/hip_bf16.h>
#include <math.h>

// ---------------------------------------------------------------------------
// Full U-Mamba block. Convs: bf16 MFMA implicit GEMM (zero-padded channels-
// last input). Mamba: fp32 LDS-resident per-sequence blocks (unchanged R1).
// Shapes: x [2,64,32,32,32]; conv 64->64 k=3 p=1; mamba: 2048 seqs x l=32,
// C=64, d_inner=128, d_state=16, d_conv=4.
// ---------------------------------------------------------------------------

typedef __attribute__((ext_vector_type(8))) short short8;   // 8 bf16 = 4 VGPR
typedef __attribute__((ext_vector_type(4))) float f32x4;

__device__ __forceinline__ float siluf(float x){ return x * (1.0f / (1.0f + __expf(-x))); }
__device__ __forceinline__ float softplusf(float x){ return fmaxf(x, 0.0f) + log1pf(__expf(-fabsf(x))); }

// ---------------------------------------------------------------------------
// Zero the padded channels-last input buffer (border stays 0 forever).
// xpad: [b][34][34][34][64] bf16 = 5,030,912 elements = 628,864 uint4.
// ---------------------------------------------------------------------------
__global__ __launch_bounds__(256) void zero_k(uint4* __restrict__ p, int n)
{
  int i = blockIdx.x * 256 + threadIdx.x;
  if (i < n){ uint4 z; z.x = z.y = z.z = z.w = 0u; p[i] = z; }
}

// ---------------------------------------------------------------------------
// Pack fp32 NCDHW -> padded channels-last bf16 [b][h+1][w+1][d+1][c].
// One block per (b,h,w); LDS transpose for coalescing both sides.
// ---------------------------------------------------------------------------
__global__ __launch_bounds__(256) void pack_k(const float* __restrict__ xin,
                                              __hip_bfloat16* __restrict__ xpad)
{
  __shared__ float lds[64 * 33];
  const int t = threadIdx.x, blk = blockIdx.x;
  const int b = blk >> 10, h = (blk >> 5) & 31, w = blk & 31;
  const size_t rbase = ((size_t)(b * 64) << 15) + h * 1024 + w * 32;
  #pragma unroll
  for (int r = 0; r < 8; r++){
    int c = r * 8 + (t >> 5), d = t & 31;
    lds[c * 33 + d] = xin[rbase + (size_t)c * 32768 + d];
  }
  __syncthreads();
  const size_t wbase = (size_t)b * 2515456 + (size_t)(h + 1) * 73984 + (w + 1) * 2176 + 64;
  #pragma unroll
  for (int r = 0; r < 8; r++){
    int d = r * 4 + (t >> 6), c = t & 63;
    xpad[wbase + d * 64 + c] = __float2bfloat16(lds[c * 33 + d]);
  }
}

// ---------------------------------------------------------------------------
// Pack conv weights fp32 [co][ci][27] -> bf16 [tap][co][ci].
// ---------------------------------------------------------------------------
__global__ __launch_bounds__(256) void wpack_k(const float* __restrict__ wt,
                                               __hip_bfloat16* __restrict__ W4)
{
  int i = blockIdx.x * 256 + threadIdx.x;   // 110592
  if (i < 110592){
    int tap = i >> 12, co = (i >> 6) & 63, ci = i & 63;
    W4[i] = __float2bfloat16(wt[(co * 64 + ci) * 27 + tap]);
  }
}

// ---------------------------------------------------------------------------
// Conv3d as implicit GEMM, bf16 MFMA 16x16x32, fp32 accum.
// Block = 256 thr = 4 waves; block tile: all 64 c_out x 128 spatial
// (1 h-row x 4 w x 32 d). Wave w owns w-column w0+w, both d-halves.
// A = weights [co][ci] (frag: 16B global load from W4, L1-hot).
// B = input   [spatial][ci] (frag: 16B global load from padded CL buffer).
// C rows = co, cols = spatial -> contiguous 64B stores.
// K = 27 taps x 64 ci = 1728, stepped 32 per MFMA. No LDS, no predicates.
// grid (256, 1, 2); conv bias dropped (canceled exactly by InstanceNorm).
// ---------------------------------------------------------------------------
__global__ __launch_bounds__(256) void conv_mfma_k(const __hip_bfloat16* __restrict__ xpad,
    const __hip_bfloat16* __restrict__ W4, float* __restrict__ y)
{
  const int t = threadIdx.x;
  const int wave = t >> 6, lane = t & 63;
  const int quad = lane >> 4, ln = lane & 15;
  const int tile = blockIdx.x, b = blockIdx.z;
  const int h = tile >> 3, w0 = (tile & 7) * 4;

  f32x4 acc[2][4];
  #pragma unroll
  for (int j = 0; j < 2; j++)
    #pragma unroll
    for (int m = 0; m < 4; m++) acc[j][m] = (f32x4){0.f, 0.f, 0.f, 0.f};

  // per-lane bases (bf16 element units)
  const size_t ib0 = (size_t)b * 2515456 + (size_t)h * 73984 + (size_t)(w0 + wave) * 2176
                     + (size_t)ln * 64 + quad * 8;          // jn=0 (d = ln)
  const size_t ib1 = ib0 + 16 * 64;                         // jn=1 (d = 16+ln)
  const int wbase = ln * 64 + quad * 8;                     // within W4 tap block

  for (int ki = 0; ki < 3; ki++){
    #pragma unroll
    for (int kj = 0; kj < 3; kj++){
      #pragma unroll
      for (int kk = 0; kk < 3; kk++){
        const int toff = ki * 73984 + kj * 2176 + kk * 64;
        const int wt_tap = (ki * 9 + kj * 3 + kk) * 4096;
        #pragma unroll
        for (int ch = 0; ch < 2; ch++){
          const int o = toff + ch * 32;
          short8 bv0 = *(const short8*)(xpad + ib0 + o);
          short8 bv1 = *(const short8*)(xpad + ib1 + o);
          const int wo = wt_tap + ch * 32 + wbase;
          short8 a0 = *(const short8*)(W4 + wo);
          short8 a1 = *(const short8*)(W4 + wo + 1024);
          short8 a2 = *(const short8*)(W4 + wo + 2048);
          short8 a3 = *(const short8*)(W4 + wo + 3072);
          acc[0][0] = __builtin_amdgcn_mfma_f32_16x16x32_bf16(a0, bv0, acc[0][0], 0, 0, 0);
          acc[0][1] = __builtin_amdgcn_mfma_f32_16x16x32_bf16(a1, bv0, acc[0][1], 0, 0, 0);
          acc[0][2] = __builtin_amdgcn_mfma_f32_16x16x32_bf16(a2, bv0, acc[0][2], 0, 0, 0);
          acc[0][3] = __builtin_amdgcn_mfma_f32_16x16x32_bf16(a3, bv0, acc[0][3], 0, 0, 0);
          acc[1][0] = __builtin_amdgcn_mfma_f32_16x16x32_bf16(a0, bv1, acc[1][0], 0, 0, 0);
          acc[1][1] = __builtin_amdgcn_mfma_f32_16x16x32_bf16(a1, bv1, acc[1][1], 0, 0, 0);
          acc[1][2] = __builtin_amdgcn_mfma_f32_16x16x32_bf16(a2, bv1, acc[1][2], 0, 0, 0);
          acc[1][3] = __builtin_amdgcn_mfma_f32_16x16x32_bf16(a3, bv1, acc[1][3], 0, 0, 0);
        }
      }
    }
  }

  // C/D: col = lane&15 (spatial d within half), row = quad*4+reg (co within tile)
  const size_t sbase = (size_t)h * 1024 + (w0 + wave) * 32 + ln;
  #pragma unroll
  for (int jn = 0; jn < 2; jn++){
    #pragma unroll
    for (int mt = 0; mt < 4; mt++){
      #pragma unroll
      for (int reg = 0; reg < 4; reg++){
        int co = mt * 16 + quad * 4 + reg;
        y[(((size_t)(b * 64 + co)) << 15) + sbase + jn * 16] = acc[jn][mt][reg];
      }
    }
  }
}

// ---------------------------------------------------------------------------
// InstanceNorm3d stats: one block per (b,c) group of 32768 elements.
// ---------------------------------------------------------------------------
__global__ __launch_bounds__(256) void inorm_stats_k(const float* __restrict__ y,
                                                     float* __restrict__ stats)
{
  __shared__ float ss[256], ss2[256];
  const int t = threadIdx.x, g = blockIdx.x;
  const float* p = y + (size_t)g * 32768;
  float s = 0.0f, s2 = 0.0f;
  for (int i = t; i < 32768; i += 256){ float v = p[i]; s += v; s2 += v * v; }
  ss[t] = s; ss2[t] = s2;
  __syncthreads();
  for (int off = 128; off > 0; off >>= 1){
    if (t < off){ ss[t] += ss[t + off]; ss2[t] += ss2[t + off]; }
    __syncthreads();
  }
  if (t == 0){
    float mu = ss[0] * (1.0f / 32768.0f);
    float var = ss2[0] * (1.0f / 32768.0f) - mu * mu;
    stats[g] = mu;
    stats[128 + g] = rsqrtf(var + 1e-5f);
  }
}

__global__ __launch_bounds__(256) void inorm_apply_k(const float* __restrict__ xin,
    const float* __restrict__ y, const float* __restrict__ stats, float* __restrict__ xout)
{
  int i = blockIdx.x * 256 + threadIdx.x;
  int g = i >> 15;
  float v = (y[i] - stats[g]) * stats[128 + g];
  v = (v >= 0.0f) ? v : 0.01f * v;
  xout[i] = xin[i] + v;
}

// ---------------------------------------------------------------------------
// Mamba weight pre-transpose (same as R1).
// ---------------------------------------------------------------------------
__global__ __launch_bounds__(256) void transpose_weights_k(
    const float* __restrict__ lw, const float* __restrict__ rw, const float* __restrict__ dw,
    const float* __restrict__ bw, const float* __restrict__ cw, const float* __restrict__ ow,
    float* __restrict__ T)
{
  int i = blockIdx.x * 256 + threadIdx.x;   // 45056 total
  if (i < 8192){ int c = i >> 7, dd = i & 127; T[i] = lw[dd * 64 + c]; }
  else if (i < 16384){ int j = i - 8192;  int c = j >> 7, dd = j & 127; T[i] = rw[dd * 64 + c]; }
  else if (i < 32768){ int j = i - 16384; int k = j >> 7, dd = j & 127; T[i] = dw[dd * 128 + k]; }
  else if (i < 34816){ int j = i - 32768; int dd = j >> 4, s = j & 15;  T[i] = bw[s * 128 + dd]; }
  else if (i < 36864){ int j = i - 34816; int dd = j >> 4, s = j & 15;  T[i] = cw[s * 128 + dd]; }
  else if (i < 45056){ int j = i - 36864; int dd = j >> 6, c = j & 63;  T[i] = ow[c * 128 + dd]; }
}

// ---------------------------------------------------------------------------
// Mamba: one block per sequence (2048), 256 threads (same as R1).
// ---------------------------------------------------------------------------
__global__ __launch_bounds__(256) void mamba_k(
    const float* __restrict__ x2, const float* __restrict__ ln_w, const float* __restrict__ ln_b,
    const float* __restrict__ Twt, const float* __restrict__ cw, const float* __restrict__ cb,
    const float* __restrict__ db, const float* __restrict__ alog,
    const float* __restrict__ pnw, const float* __restrict__ pnb,
    const float* __restrict__ axw, float* __restrict__ accum, int axis, int first)
{
  __shared__ __align__(16) float smem[15808];
  float* s_ln = smem;            // [64][36]
  float* s_a  = smem + 2304;     // [128][33]
  float* s_xl = smem + 6528;     // [128][36]; holes: C; rows<64 reused for out
  float* s_y  = smem + 11136;    // [128][36]; holes: B
  float* s_mu = smem + 15744;
  float* s_rs = smem + 15776;

  const float* lT = Twt;
  const float* rT = Twt + 8192;
  const float* dT = Twt + 16384;
  const float* bT = Twt + 32768;
  const float* cT = Twt + 34816;
  const float* oT = Twt + 36864;

  const int t = threadIdx.x;
  const int n = blockIdx.x;
  const int b = n >> 10, r1 = (n >> 5) & 31, r0 = n & 31;
  size_t base; int lstride;
  if (axis == 0){      base = ((size_t)b << 21) + (r1 << 5)  + r0;        lstride = 1024; }
  else if (axis == 1){ base = ((size_t)b << 21) + (r1 << 10) + r0;        lstride = 32;   }
  else {               base = ((size_t)b << 21) + (r1 << 10) + (r0 << 5); lstride = 1;    }

  for (int i = t; i < 2048; i += 256){
    int c = i >> 5, l = i & 31;
    s_ln[c * 36 + l] = x2[base + (size_t)c * 32768 + (size_t)l * lstride];
  }
  __syncthreads();

  if (t < 32){
    float s = 0.0f, s2 = 0.0f;
    for (int c = 0; c < 64; c++){ float v = s_ln[c * 36 + t]; s += v; s2 += v * v; }
    float mu = s * (1.0f / 64.0f);
    float var = s2 * (1.0f / 64.0f) - mu * mu;
    s_mu[t] = mu; s_rs[t] = rsqrtf(var + 1e-5f);
  }
  __syncthreads();

  for (int i = t; i < 2048; i += 256){
    int c = i >> 5, l = i & 31;
    s_ln[c * 36 + l] = (s_ln[c * 36 + l] - s_mu[l]) * s_rs[l] * ln_w[c] + ln_b[c];
  }
  __syncthreads();

  {
    const int dd = t & 127, l0 = (t >> 7) * 16;
    float acc[16];
    #pragma unroll
    for (int j = 0; j < 16; j++) acc[j] = 0.0f;
    #pragma unroll 4
    for (int c = 0; c < 64; c++){
      float wv = lT[c * 128 + dd];
      #pragma unroll
      for (int q = 0; q < 4; q++){
        float4 xv = *(const float4*)&s_ln[c * 36 + l0 + q * 4];
        acc[q*4+0] += wv * xv.x; acc[q*4+1] += wv * xv.y;
        acc[q*4+2] += wv * xv.z; acc[q*4+3] += wv * xv.w;
      }
    }
    #pragma unroll
    for (int j = 0; j < 16; j++) s_a[dd * 33 + l0 + j] = acc[j];
  }
  __syncthreads();

  {
    const int dd = t & 127, l0 = (t >> 7) * 16;
    float4 cwv = *(const float4*)&cw[dd * 4];
    float bb = cb[dd];
    float vm3, vm2, vm1;
    if (l0 == 0){ vm3 = vm2 = vm1 = 0.0f; }
    else { vm3 = s_a[dd*33 + l0 - 3]; vm2 = s_a[dd*33 + l0 - 2]; vm1 = s_a[dd*33 + l0 - 1]; }
    #pragma unroll
    for (int j = 0; j < 16; j++){
      float cur = s_a[dd * 33 + l0 + j];
      float v = bb + cwv.x * vm3 + cwv.y * vm2 + cwv.z * vm1 + cwv.w * cur;
      s_xl[dd * 36 + l0 + j] = siluf(v);
      vm3 = vm2; vm2 = vm1; vm1 = cur;
    }
  }
  __syncthreads();

  {
    const int dd = t & 127, l0 = (t >> 7) * 16;
    float acc[16];
    #pragma unroll
    for (int j = 0; j < 16; j++) acc[j] = 0.0f;
    #pragma unroll 4
    for (int k = 0; k < 128; k++){
      float wv = dT[k * 128 + dd];
      #pragma unroll
      for (int q = 0; q < 4; q++){
        float4 xv = *(const float4*)&s_xl[k * 36 + l0 + q * 4];
        acc[q*4+0] += wv * xv.x; acc[q*4+1] += wv * xv.y;
        acc[q*4+2] += wv * xv.z; acc[q*4+3] += wv * xv.w;
      }
    }
    float bb = db[dd];
    #pragma unroll
    for (int j = 0; j < 16; j++){
      float z = softplusf(acc[j] + bb);
      s_a[dd * 33 + l0 + j] = fminf(fmaxf(z, 1e-4f), 10.0f);
    }
  }
  {
    const int s = t & 15, which = (t >> 4) & 1, lg = t >> 5;
    const int l0 = lg * 4;
    const float* W = which ? cT : bT;
    float acc4[4] = {0.0f, 0.0f, 0.0f, 0.0f};
    #pragma unroll 4
    for (int k = 0; k < 128; k++){
      float wv = W[k * 16 + s];
      float4 xv = *(const float4*)&s_xl[k * 36 + l0];
      acc4[0] += wv * xv.x; acc4[1] += wv * xv.y; acc4[2] += wv * xv.z; acc4[3] += wv * xv.w;
    }
    float* H = which ? s_xl : s_y;
    #pragma unroll
    for (int j = 0; j < 4; j++){
      int ib = (l0 + j) * 16 + s;
      H[(ib >> 2) * 36 + 32 + (ib & 3)] = acc4[j];
    }
  }
  __syncthreads();

  if (t < 128){
    float A[16], h[16];
    #pragma unroll
    for (int s = 0; s < 16; s++){ A[s] = -softplusf(alog[s]); h[s] = 0.0f; }
    const int dd = t;
    for (int l = 0; l < 32; l++){
      float dt = s_a[dd * 33 + l];
      float xt = s_xl[dd * 36 + l];
      float dx = dt * xt;
      float yv = 0.0f;
      #pragma unroll
      for (int s = 0; s < 16; s++){
        int ib = l * 16 + s;
        float Bv = s_y[(ib >> 2) * 36 + 32 + (ib & 3)];
        float Cv = s_xl[(ib >> 2) * 36 + 32 + (ib & 3)];
        h[s] = __expf(dt * A[s]) * h[s] + dx * Bv;
        yv += h[s] * Cv;
      }
      s_y[dd * 36 + l] = yv;
    }
  }
  __syncthreads();

  {
    const int dd = t & 127, l0 = (t >> 7) * 16;
    float acc[16];
    #pragma unroll
    for (int j = 0; j < 16; j++) acc[j] = 0.0f;
    #pragma unroll 4
    for (int c = 0; c < 64; c++){
      float wv = rT[c * 128 + dd];
      #pragma unroll
      for (int q = 0; q < 4; q++){
        float4 xv = *(const float4*)&s_ln[c * 36 + l0 + q * 4];
        acc[q*4+0] += wv * xv.x; acc[q*4+1] += wv * xv.y;
        acc[q*4+2] += wv * xv.z; acc[q*4+3] += wv * xv.w;
      }
    }
    #pragma unroll
    for (int j = 0; j < 16; j++) s_y[dd * 36 + l0 + j] *= siluf(acc[j]);
  }
  __syncthreads();

  if (t < 32){
    float s = 0.0f, s2 = 0.0f;
    for (int k = 0; k < 128; k++){ float v = s_y[k * 36 + t]; s += v; s2 += v * v; }
    float mu = s * (1.0f / 128.0f);
    float var = s2 * (1.0f / 128.0f) - mu * mu;
    s_mu[t] = mu; s_rs[t] = rsqrtf(var + 1e-5f);
  }
  __syncthreads();

  for (int i = t; i < 4096; i += 256){
    int dd = i >> 5, l = i & 31;
    s_y[dd * 36 + l] = (s_y[dd * 36 + l] - s_mu[l]) * s_rs[l] * pnw[dd] + pnb[dd];
  }
  __syncthreads();

  {
    const int c = t & 63, lg = t >> 6, l0 = lg * 8;
    float acc[8];
    #pragma unroll
    for (int j = 0; j < 8; j++) acc[j] = 0.0f;
    #pragma unroll 4
    for (int k = 0; k < 128; k++){
      float wv = oT[k * 64 + c];
      float4 a  = *(const float4*)&s_y[k * 36 + l0];
      float4 b4 = *(const float4*)&s_y[k * 36 + l0 + 4];
      acc[0] += wv * a.x;  acc[1] += wv * a.y;  acc[2] += wv * a.z;  acc[3] += wv * a.w;
      acc[4] += wv * b4.x; acc[5] += wv * b4.y; acc[6] += wv * b4.z; acc[7] += wv * b4.w;
    }
    #pragma unroll
    for (int j = 0; j < 8; j++) s_xl[c * 36 + l0 + j] = acc[j];
  }
  __syncthreads();

  float a0 = axw[0], a1 = axw[1], a2 = axw[2];
  float mx = fmaxf(a0, fmaxf(a1, a2));
  float e0 = __expf(a0 - mx), e1 = __expf(a1 - mx), e2 = __expf(a2 - mx);
  float wax = ((axis == 0) ? e0 : (axis == 1) ? e1 : e2) / (e0 + e1 + e2);
  for (int i = t; i < 2048; i += 256){
    int c = i >> 5, l = i & 31;
    float v = wax * s_xl[c * 36 + l];
    size_t idx = base + (size_t)c * 32768 + (size_t)l * lstride;
    if (first) accum[idx] = v;
    else       accum[idx] += v;
  }
}

__global__ __launch_bounds__(256) void final_k(const float* __restrict__ x,
    const float* __restrict__ rs, float* __restrict__ out)
{
  int i = blockIdx.x * 256 + threadIdx.x;
  out[i] = x[i] + rs[0] * out[i];
}

// ---------------------------------------------------------------------------
extern "C" void kernel_launch(void* const* d_in, const int* in_sizes, int n_in,
                              void* d_out, int out_size, void* d_ws, size_t ws_size,
                              hipStream_t stream)
{
  const float* x      = (const float*)d_in[0];
  const float* cr1w   = (const float*)d_in[1];
  const float* cr2w   = (const float*)d_in[3];
  const float* ln_w   = (const float*)d_in[5];
  const float* ln_b   = (const float*)d_in[6];
  const float* left_w = (const float*)d_in[7];
  const float* c1dw   = (const float*)d_in[8];
  const float* c1db   = (const float*)d_in[9];
  const float* dw     = (const float*)d_in[10];
  const float* db     = (const float*)d_in[11];
  const float* bpw    = (const float*)d_in[12];
  const float* cpw    = (const float*)d_in[13];
  const float* alog   = (const float*)d_in[14];
  const float* rw     = (const float*)d_in[15];
  const float* pnw    = (const float*)d_in[16];
  const float* pnb    = (const float*)d_in[17];
  const float* ow     = (const float*)d_in[18];
  const float* rsc    = (const float*)d_in[19];
  const float* axw    = (const float*)d_in[20];
  float* out = (float*)d_out;                       // doubles as conv raw-out buffer
  float* wsf = (float*)d_ws;

  float* buf1  = wsf;                               // 4,194,304 f: x1 -> x2
  float* stats = wsf + 4194304;                     // 256 f
  float* Twt   = wsf + 4194304 + 256;               // 45,056 f
  __hip_bfloat16* xpad = (__hip_bfloat16*)(wsf + 4239616);   // 5,030,912 bf16 (16B-aligned)
  __hip_bfloat16* W4a  = xpad + 5030912;            // 110,592 bf16
  __hip_bfloat16* W4b  = W4a + 110592;              // 110,592 bf16

  zero_k<<<2457, 256, 0, stream>>>((uint4*)xpad, 628864);
  wpack_k<<<432, 256, 0, stream>>>(cr1w, W4a);
  wpack_k<<<432, 256, 0, stream>>>(cr2w, W4b);
  transpose_weights_k<<<176, 256, 0, stream>>>(left_w, rw, dw, bpw, cpw, ow, Twt);

  dim3 cgrid(256, 1, 2);
  // conv-res block 1 (raw conv out in d_out)
  pack_k<<<2048, 256, 0, stream>>>(x, xpad);
  conv_mfma_k<<<cgrid, 256, 0, stream>>>(xpad, W4a, out);
  inorm_stats_k<<<128, 256, 0, stream>>>(out, stats);
  inorm_apply_k<<<16384, 256, 0, stream>>>(x, out, stats, buf1);
  // conv-res block 2
  pack_k<<<2048, 256, 0, stream>>>(buf1, xpad);
  conv_mfma_k<<<cgrid, 256, 0, stream>>>(xpad, W4b, out);
  inorm_stats_k<<<128, 256, 0, stream>>>(out, stats);
  inorm_apply_k<<<16384, 256, 0, stream>>>(buf1, out, stats, buf1);
  // three axis-wise mamba passes, accumulate into d_out (first overwrites)
  for (int axis = 0; axis < 3; axis++)
    mamba_k<<<2048, 256, 0, stream>>>(buf1, ln_w, ln_b, Twt, c1dw, c1db, db, alog,
                                      pnw, pnb, axw, out, axis, axis == 0 ? 1 : 0);
  final_k<<<16384, 256, 0, stream>>>(x, rsc, out);
}

// Round 3
// 837.030 us; speedup vs baseline: 2.6728x; 1.4966x over previous
//
#include <hip/hip_runtime.h>
#include <hip/hip_bf16.h>
#include <math.h>

// ---------------------------------------------------------------------------
// Full U-Mamba block. Convs: bf16 MFMA implicit GEMM (R2, unchanged).
// Mamba (R3): restructured from per-sequence megakernel into big position-wise
// MFMA GEMMs (axis-independent parts hoisted & computed once) + a light
// per-sequence scan kernel for the truly sequential part.
// ---------------------------------------------------------------------------

typedef __attribute__((ext_vector_type(8))) short short8;   // 8 bf16 = 4 VGPR
typedef __attribute__((ext_vector_type(4))) float f32x4;

__device__ __forceinline__ float siluf(float x){ return x * (1.0f / (1.0f + __expf(-x))); }
__device__ __forceinline__ float softplusf(float x){ return fmaxf(x, 0.0f) + log1pf(__expf(-fabsf(x))); }
__device__ __forceinline__ float b2f(short s){
  unsigned int u = ((unsigned int)(unsigned short)s) << 16;
  float f; __builtin_memcpy(&f, &u, 4); return f;
}
__device__ __forceinline__ short f2b(float v){
  __hip_bfloat16 h = __float2bfloat16(v);
  unsigned short u; __builtin_memcpy(&u, &h, 2); return (short)u;
}

// ---------------------------------------------------------------------------
// Zero padded channels-last conv input. xpad: [b][34][34][34][64] bf16.
// ---------------------------------------------------------------------------
__global__ __launch_bounds__(256) void zero_k(uint4* __restrict__ p, int n)
{
  int i = blockIdx.x * 256 + threadIdx.x;
  if (i < n){ uint4 z; z.x = z.y = z.z = z.w = 0u; p[i] = z; }
}

// ---------------------------------------------------------------------------
// Pack fp32 NCDHW -> padded channels-last bf16 [b][h+1][w+1][d+1][c].
// ---------------------------------------------------------------------------
__global__ __launch_bounds__(256) void pack_k(const float* __restrict__ xin,
                                              __hip_bfloat16* __restrict__ xpad)
{
  __shared__ float lds[64 * 33];
  const int t = threadIdx.x, blk = blockIdx.x;
  const int b = blk >> 10, h = (blk >> 5) & 31, w = blk & 31;
  const size_t rbase = ((size_t)(b * 64) << 15) + h * 1024 + w * 32;
  #pragma unroll
  for (int r = 0; r < 8; r++){
    int c = r * 8 + (t >> 5), d = t & 31;
    lds[c * 33 + d] = xin[rbase + (size_t)c * 32768 + d];
  }
  __syncthreads();
  const size_t wbase = (size_t)b * 2515456 + (size_t)(h + 1) * 73984 + (w + 1) * 2176 + 64;
  #pragma unroll
  for (int r = 0; r < 8; r++){
    int d = r * 4 + (t >> 6), c = t & 63;
    xpad[wbase + d * 64 + c] = __float2bfloat16(lds[c * 33 + d]);
  }
}

// Pack conv weights fp32 [co][ci][27] -> bf16 [tap][co][ci].
__global__ __launch_bounds__(256) void wpack_k(const float* __restrict__ wt,
                                               __hip_bfloat16* __restrict__ W4)
{
  int i = blockIdx.x * 256 + threadIdx.x;   // 110592
  if (i < 110592){
    int tap = i >> 12, co = (i >> 6) & 63, ci = i & 63;
    W4[i] = __float2bfloat16(wt[(co * 64 + ci) * 27 + tap]);
  }
}

// ---------------------------------------------------------------------------
// Conv3d as implicit GEMM, bf16 MFMA 16x16x32 (R2, unchanged; bias canceled
// by InstanceNorm and dropped).
// ---------------------------------------------------------------------------
__global__ __launch_bounds__(256) void conv_mfma_k(const __hip_bfloat16* __restrict__ xpad,
    const __hip_bfloat16* __restrict__ W4, float* __restrict__ y)
{
  const int t = threadIdx.x;
  const int wave = t >> 6, lane = t & 63;
  const int quad = lane >> 4, ln = lane & 15;
  const int tile = blockIdx.x, b = blockIdx.z;
  const int h = tile >> 3, w0 = (tile & 7) * 4;

  f32x4 acc[2][4];
  #pragma unroll
  for (int j = 0; j < 2; j++)
    #pragma unroll
    for (int m = 0; m < 4; m++) acc[j][m] = (f32x4){0.f, 0.f, 0.f, 0.f};

  const size_t ib0 = (size_t)b * 2515456 + (size_t)h * 73984 + (size_t)(w0 + wave) * 2176
                     + (size_t)ln * 64 + quad * 8;
  const size_t ib1 = ib0 + 16 * 64;
  const int wbase = ln * 64 + quad * 8;

  for (int ki = 0; ki < 3; ki++){
    #pragma unroll
    for (int kj = 0; kj < 3; kj++){
      #pragma unroll
      for (int kk = 0; kk < 3; kk++){
        const int toff = ki * 73984 + kj * 2176 + kk * 64;
        const int wt_tap = (ki * 9 + kj * 3 + kk) * 4096;
        #pragma unroll
        for (int ch = 0; ch < 2; ch++){
          const int o = toff + ch * 32;
          short8 bv0 = *(const short8*)(xpad + ib0 + o);
          short8 bv1 = *(const short8*)(xpad + ib1 + o);
          const int wo = wt_tap + ch * 32 + wbase;
          short8 a0 = *(const short8*)(W4 + wo);
          short8 a1 = *(const short8*)(W4 + wo + 1024);
          short8 a2 = *(const short8*)(W4 + wo + 2048);
          short8 a3 = *(const short8*)(W4 + wo + 3072);
          acc[0][0] = __builtin_amdgcn_mfma_f32_16x16x32_bf16(a0, bv0, acc[0][0], 0, 0, 0);
          acc[0][1] = __builtin_amdgcn_mfma_f32_16x16x32_bf16(a1, bv0, acc[0][1], 0, 0, 0);
          acc[0][2] = __builtin_amdgcn_mfma_f32_16x16x32_bf16(a2, bv0, acc[0][2], 0, 0, 0);
          acc[0][3] = __builtin_amdgcn_mfma_f32_16x16x32_bf16(a3, bv0, acc[0][3], 0, 0, 0);
          acc[1][0] = __builtin_amdgcn_mfma_f32_16x16x32_bf16(a0, bv1, acc[1][0], 0, 0, 0);
          acc[1][1] = __builtin_amdgcn_mfma_f32_16x16x32_bf16(a1, bv1, acc[1][1], 0, 0, 0);
          acc[1][2] = __builtin_amdgcn_mfma_f32_16x16x32_bf16(a2, bv1, acc[1][2], 0, 0, 0);
          acc[1][3] = __builtin_amdgcn_mfma_f32_16x16x32_bf16(a3, bv1, acc[1][3], 0, 0, 0);
        }
      }
    }
  }

  const size_t sbase = (size_t)h * 1024 + (w0 + wave) * 32 + ln;
  #pragma unroll
  for (int jn = 0; jn < 2; jn++){
    #pragma unroll
    for (int mt = 0; mt < 4; mt++){
      #pragma unroll
      for (int reg = 0; reg < 4; reg++){
        int co = mt * 16 + quad * 4 + reg;
        y[(((size_t)(b * 64 + co)) << 15) + sbase + jn * 16] = acc[jn][mt][reg];
      }
    }
  }
}

// ---------------------------------------------------------------------------
// InstanceNorm3d (R2, unchanged).
// ---------------------------------------------------------------------------
__global__ __launch_bounds__(256) void inorm_stats_k(const float* __restrict__ y,
                                                     float* __restrict__ stats)
{
  __shared__ float ss[256], ss2[256];
  const int t = threadIdx.x, g = blockIdx.x;
  const float* p = y + (size_t)g * 32768;
  float s = 0.0f, s2 = 0.0f;
  for (int i = t; i < 32768; i += 256){ float v = p[i]; s += v; s2 += v * v; }
  ss[t] = s; ss2[t] = s2;
  __syncthreads();
  for (int off = 128; off > 0; off >>= 1){
    if (t < off){ ss[t] += ss[t + off]; ss2[t] += ss2[t + off]; }
    __syncthreads();
  }
  if (t == 0){
    float mu = ss[0] * (1.0f / 32768.0f);
    float var = ss2[0] * (1.0f / 32768.0f) - mu * mu;
    stats[g] = mu;
    stats[128 + g] = rsqrtf(var + 1e-5f);
  }
}

__global__ __launch_bounds__(256) void inorm_apply_k(const float* __restrict__ xin,
    const float* __restrict__ y, const float* __restrict__ stats, float* __restrict__ xout)
{
  int i = blockIdx.x * 256 + threadIdx.x;
  int g = i >> 15;
  float v = (y[i] - stats[g]) * stats[128 + g];
  v = (v >= 0.0f) ? v : 0.01f * v;
  xout[i] = xin[i] + v;
}

// ---------------------------------------------------------------------------
// Mamba weight prep: bf16 casts into GEMM-friendly row-major [N][K] tables.
// Wlr [256][64]  (rows 0-127 left_w, 128-255 right_w)
// Wd  [160][128] (0-127 delta_w, 128-143 Bp_w, 144-159 Cp_w)
// oW  [64][128]  (out_w direct)
// ---------------------------------------------------------------------------
__global__ __launch_bounds__(256) void mamba_wprep_k(
    const float* __restrict__ lw, const float* __restrict__ rw, const float* __restrict__ dw,
    const float* __restrict__ bw, const float* __restrict__ cwp, const float* __restrict__ ow,
    __hip_bfloat16* __restrict__ Wlr, __hip_bfloat16* __restrict__ Wd,
    __hip_bfloat16* __restrict__ oWp)
{
  int i = blockIdx.x * 256 + threadIdx.x;
  if (i < 16384){
    int row = i >> 6, c = i & 63;
    float v = (row < 128) ? lw[row * 64 + c] : rw[(row - 128) * 64 + c];
    Wlr[i] = __float2bfloat16(v);
  } else if (i < 36864){
    int j = i - 16384; int row = j >> 7, k = j & 127;
    float v = (row < 128) ? dw[row * 128 + k]
            : (row < 144 ? bw[(row - 128) * 128 + k] : cwp[(row - 144) * 128 + k]);
    Wd[j] = __float2bfloat16(v);
  } else if (i < 45056){
    int j = i - 36864;
    oWp[j] = __float2bfloat16(ow[j]);
  }
}

// ---------------------------------------------------------------------------
// LayerNorm over C + NCDHW -> channels-last bf16 [pos][64].
// pos = b*32768 + h*1024 + w*32 + d. Axis-independent: done ONCE.
// ---------------------------------------------------------------------------
__global__ __launch_bounds__(256) void ln_k(const float* __restrict__ x2,
    const float* __restrict__ lnw, const float* __restrict__ lnb,
    __hip_bfloat16* __restrict__ lnx)
{
  __shared__ float lds[64 * 33];
  __shared__ float s_mu[32], s_rs[32];
  const int t = threadIdx.x, blk = blockIdx.x;
  const int b = blk >> 10, h = (blk >> 5) & 31, w = blk & 31;
  const size_t rbase = ((size_t)(b * 64) << 15) + h * 1024 + w * 32;
  #pragma unroll
  for (int r = 0; r < 8; r++){
    int c = r * 8 + (t >> 5), d = t & 31;
    lds[c * 33 + d] = x2[rbase + (size_t)c * 32768 + d];
  }
  __syncthreads();
  if (t < 32){
    float s = 0.f, s2 = 0.f;
    for (int c = 0; c < 64; c++){ float v = lds[c * 33 + t]; s += v; s2 += v * v; }
    float mu = s * (1.f / 64.f);
    float var = s2 * (1.f / 64.f) - mu * mu;
    s_mu[t] = mu; s_rs[t] = rsqrtf(var + 1e-5f);
  }
  __syncthreads();
  const int d = t >> 3, c0 = (t & 7) * 8;
  const int pos = b * 32768 + h * 1024 + w * 32 + d;
  const float mu = s_mu[d], rs = s_rs[d];
  short8 o;
  #pragma unroll
  for (int j = 0; j < 8; j++){
    int c = c0 + j;
    o[j] = f2b((lds[c * 33 + d] - mu) * rs * lnw[c] + lnb[c]);
  }
  *(short8*)&lnx[(size_t)pos * 64 + c0] = o;
}

// ---------------------------------------------------------------------------
// GEMM [65536,64] x [64,256] -> Lbuf (cols 0-127, raw) + Gbuf (silu, 128-255).
// Axis-independent: done ONCE. Wave: 16 pos x 256 cols, K=64.
// ---------------------------------------------------------------------------
__global__ __launch_bounds__(256) void gemm_lr_k(const __hip_bfloat16* __restrict__ lnx,
    const __hip_bfloat16* __restrict__ Wlr, __hip_bfloat16* __restrict__ Lb,
    __hip_bfloat16* __restrict__ Gb)
{
  const int t = threadIdx.x, wave = t >> 6, lane = t & 63, quad = lane >> 4, ln = lane & 15;
  const int pos0 = blockIdx.x * 64 + wave * 16;
  f32x4 acc[16];
  #pragma unroll
  for (int nt = 0; nt < 16; nt++) acc[nt] = (f32x4){0.f, 0.f, 0.f, 0.f};
  #pragma unroll
  for (int ks = 0; ks < 2; ks++){
    short8 a = *(const short8*)&lnx[(size_t)(pos0 + ln) * 64 + ks * 32 + quad * 8];
    #pragma unroll
    for (int nt = 0; nt < 16; nt++){
      short8 bv = *(const short8*)&Wlr[(nt * 16 + ln) * 64 + ks * 32 + quad * 8];
      acc[nt] = __builtin_amdgcn_mfma_f32_16x16x32_bf16(a, bv, acc[nt], 0, 0, 0);
    }
  }
  #pragma unroll
  for (int nt = 0; nt < 16; nt++){
    int col = nt * 16 + ln;
    #pragma unroll
    for (int reg = 0; reg < 4; reg++){
      int pos = pos0 + quad * 4 + reg;
      float v = acc[nt][reg];
      if (col < 128) Lb[(size_t)pos * 128 + col] = __float2bfloat16(v);
      else           Gb[(size_t)pos * 128 + col - 128] = __float2bfloat16(siluf(v));
    }
  }
}

// ---------------------------------------------------------------------------
// Per-axis causal depthwise conv1d(k=4) + bias + silu. Thread: 1 pos x 8 ch.
// l = (pos >> sh) & 31, sigma = 1<<sh.
// ---------------------------------------------------------------------------
__global__ __launch_bounds__(256) void conv1d_silu_k(const __hip_bfloat16* __restrict__ Lb,
    const float* __restrict__ cw, const float* __restrict__ cb,
    __hip_bfloat16* __restrict__ xl, int sh)
{
  int i = blockIdx.x * 256 + threadIdx.x;    // 1,048,576 threads
  int pos = i >> 4, c0 = (i & 15) * 8;
  int l = (pos >> sh) & 31;
  int sigma = 1 << sh;
  float acc[8]; float4 w4[8];
  #pragma unroll
  for (int c = 0; c < 8; c++){ w4[c] = *(const float4*)&cw[(c0 + c) * 4]; acc[c] = cb[c0 + c]; }
  #pragma unroll
  for (int j = 0; j < 4; j++){
    int off = 3 - j;
    if (l >= off){
      short8 lv = *(const short8*)&Lb[(size_t)(pos - off * sigma) * 128 + c0];
      #pragma unroll
      for (int c = 0; c < 8; c++){
        float wv = (j == 0) ? w4[c].x : (j == 1) ? w4[c].y : (j == 2) ? w4[c].z : w4[c].w;
        acc[c] += wv * b2f(lv[c]);
      }
    }
  }
  short8 o;
  #pragma unroll
  for (int c = 0; c < 8; c++) o[c] = f2b(siluf(acc[c]));
  *(short8*)&xl[(size_t)pos * 128 + c0] = o;
}

// ---------------------------------------------------------------------------
// GEMM [65536,128] x [128,160] -> dbc [pos][160] bf16.
// cols 0-127: delta = clip(softplus(v+db),1e-4,10); 128-143: B; 144-159: C.
// ---------------------------------------------------------------------------
__global__ __launch_bounds__(256) void gemm_dbc_k(const __hip_bfloat16* __restrict__ xl,
    const __hip_bfloat16* __restrict__ Wd, const float* __restrict__ db,
    __hip_bfloat16* __restrict__ dbc)
{
  const int t = threadIdx.x, wave = t >> 6, lane = t & 63, quad = lane >> 4, ln = lane & 15;
  const int pos0 = blockIdx.x * 64 + wave * 16;
  f32x4 acc[10];
  #pragma unroll
  for (int nt = 0; nt < 10; nt++) acc[nt] = (f32x4){0.f, 0.f, 0.f, 0.f};
  #pragma unroll
  for (int ks = 0; ks < 4; ks++){
    short8 a = *(const short8*)&xl[(size_t)(pos0 + ln) * 128 + ks * 32 + quad * 8];
    #pragma unroll
    for (int nt = 0; nt < 10; nt++){
      short8 bv = *(const short8*)&Wd[(nt * 16 + ln) * 128 + ks * 32 + quad * 8];
      acc[nt] = __builtin_amdgcn_mfma_f32_16x16x32_bf16(a, bv, acc[nt], 0, 0, 0);
    }
  }
  #pragma unroll
  for (int nt = 0; nt < 10; nt++){
    int col = nt * 16 + ln;
    bool isd = col < 128;
    float dbv = isd ? db[col] : 0.f;
    #pragma unroll
    for (int reg = 0; reg < 4; reg++){
      int pos = pos0 + quad * 4 + reg;
      float v = acc[nt][reg];
      if (isd) v = fminf(fmaxf(softplusf(v + dbv), 1e-4f), 10.f);
      dbc[(size_t)pos * 160 + col] = __float2bfloat16(v);
    }
  }
}

// ---------------------------------------------------------------------------
// Per-axis selective scan + gate + post-LN. 1 block (128 thr) per sequence.
// Thread d owns h[16] in registers. B/C staged in LDS (broadcast reads);
// y in LDS [32][129] for the post-LN over d_inner. ~21 KB LDS.
// ---------------------------------------------------------------------------
__global__ __launch_bounds__(128) void scan_k(const __hip_bfloat16* __restrict__ dbc,
    const __hip_bfloat16* __restrict__ xl, const __hip_bfloat16* __restrict__ Gb,
    const float* __restrict__ alog, const float* __restrict__ pnw, const float* __restrict__ pnb,
    __hip_bfloat16* __restrict__ Yb, int axis)
{
  __shared__ float s_B[512], s_C[512], s_y[4128], s_mu[32], s_rs[32];
  const int t = threadIdx.x, seq = blockIdx.x;
  const int b = seq >> 10, r1 = (seq >> 5) & 31, r0 = seq & 31;
  int base, sigma;
  if (axis == 0){      base = b * 32768 + r1 * 32 + r0;        sigma = 1024; }
  else if (axis == 1){ base = b * 32768 + r1 * 1024 + r0;      sigma = 32; }
  else {               base = b * 32768 + r1 * 1024 + r0 * 32; sigma = 1; }

  for (int i = t; i < 1024; i += 128){
    int l = i >> 5, j = i & 31;
    float v = __bfloat162float(dbc[(size_t)(base + l * sigma) * 160 + 128 + j]);
    if (j < 16) s_B[l * 16 + j] = v; else s_C[l * 16 + (j - 16)] = v;
  }
  float A[16], h[16];
  #pragma unroll
  for (int s = 0; s < 16; s++){ A[s] = -softplusf(alog[s]); h[s] = 0.f; }
  __syncthreads();

  const int d = t;
  for (int l = 0; l < 32; l++){
    size_t row = (size_t)(base + l * sigma);
    float dt = __bfloat162float(dbc[row * 160 + d]);
    float xt = __bfloat162float(xl[row * 128 + d]);
    float g  = __bfloat162float(Gb[row * 128 + d]);
    float dx = dt * xt, yv = 0.f;
    #pragma unroll
    for (int s = 0; s < 16; s++){
      h[s] = __expf(dt * A[s]) * h[s] + dx * s_B[l * 16 + s];
      yv += h[s] * s_C[l * 16 + s];
    }
    s_y[l * 129 + d] = yv * g;
  }
  __syncthreads();
  if (t < 32){
    float s = 0.f, s2 = 0.f;
    for (int k = 0; k < 128; k++){ float v = s_y[t * 129 + k]; s += v; s2 += v * v; }
    float mu = s * (1.f / 128.f), var = s2 * (1.f / 128.f) - mu * mu;
    s_mu[t] = mu; s_rs[t] = rsqrtf(var + 1e-5f);
  }
  __syncthreads();
  const float pw = pnw[d], pb = pnb[d];
  for (int l = 0; l < 32; l++){
    float v = (s_y[l * 129 + d] - s_mu[l]) * s_rs[l] * pw + pb;
    Yb[(size_t)(base + l * sigma) * 128 + d] = __float2bfloat16(v);
  }
}

// ---------------------------------------------------------------------------
// GEMM out: A = out_w [64co][128], B = Ybuf [pos][128]; C col=pos -> 64B-
// contiguous scatter into d_out (NCDHW), scaled by softmax(axis_w)[axis];
// accumulates across axes (first overwrites poison).
// ---------------------------------------------------------------------------
__global__ __launch_bounds__(256) void gemm_out_k(const __hip_bfloat16* __restrict__ Yb,
    const __hip_bfloat16* __restrict__ oW, const float* __restrict__ axw,
    float* __restrict__ outp, int axis, int first)
{
  const int t = threadIdx.x, wave = t >> 6, lane = t & 63, quad = lane >> 4, ln = lane & 15;
  const int pos0 = blockIdx.x * 64 + wave * 16;
  f32x4 acc[4];
  #pragma unroll
  for (int mt = 0; mt < 4; mt++) acc[mt] = (f32x4){0.f, 0.f, 0.f, 0.f};
  #pragma unroll
  for (int ks = 0; ks < 4; ks++){
    short8 bv = *(const short8*)&Yb[(size_t)(pos0 + ln) * 128 + ks * 32 + quad * 8];
    #pragma unroll
    for (int mt = 0; mt < 4; mt++){
      short8 a = *(const short8*)&oW[(mt * 16 + ln) * 128 + ks * 32 + quad * 8];
      acc[mt] = __builtin_amdgcn_mfma_f32_16x16x32_bf16(a, bv, acc[mt], 0, 0, 0);
    }
  }
  float a0 = axw[0], a1 = axw[1], a2 = axw[2];
  float mx = fmaxf(a0, fmaxf(a1, a2));
  float e0 = __expf(a0 - mx), e1 = __expf(a1 - mx), e2 = __expf(a2 - mx);
  float wax = ((axis == 0) ? e0 : (axis == 1) ? e1 : e2) / (e0 + e1 + e2);
  const int pos = pos0 + ln;
  const int bb = pos >> 15, hwd = pos & 32767;
  #pragma unroll
  for (int mt = 0; mt < 4; mt++){
    #pragma unroll
    for (int reg = 0; reg < 4; reg++){
      int co = mt * 16 + quad * 4 + reg;
      float* p = &outp[(((size_t)(bb * 64 + co)) << 15) + hwd];
      float v = acc[mt][reg] * wax;
      if (!first) v += *p;
      *p = v;
    }
  }
}

__global__ __launch_bounds__(256) void final_k(const float* __restrict__ x,
    const float* __restrict__ rs, float* __restrict__ out)
{
  int i = blockIdx.x * 256 + threadIdx.x;
  out[i] = x[i] + rs[0] * out[i];
}

// ---------------------------------------------------------------------------
extern "C" void kernel_launch(void* const* d_in, const int* in_sizes, int n_in,
                              void* d_out, int out_size, void* d_ws, size_t ws_size,
                              hipStream_t stream)
{
  const float* x      = (const float*)d_in[0];
  const float* cr1w   = (const float*)d_in[1];
  const float* cr2w   = (const float*)d_in[3];
  const float* ln_w   = (const float*)d_in[5];
  const float* ln_b   = (const float*)d_in[6];
  const float* left_w = (const float*)d_in[7];
  const float* c1dw   = (const float*)d_in[8];
  const float* c1db   = (const float*)d_in[9];
  const float* dw     = (const float*)d_in[10];
  const float* db     = (const float*)d_in[11];
  const float* bpw    = (const float*)d_in[12];
  const float* cpw    = (const float*)d_in[13];
  const float* alog   = (const float*)d_in[14];
  const float* rw     = (const float*)d_in[15];
  const float* pnw    = (const float*)d_in[16];
  const float* pnb    = (const float*)d_in[17];
  const float* ow     = (const float*)d_in[18];
  const float* rsc    = (const float*)d_in[19];
  const float* axw    = (const float*)d_in[20];
  float* out = (float*)d_out;                       // conv raw out, then mamba accum
  float* wsf = (float*)d_ws;

  // workspace layout (fp32-slot offsets); total 24,668,928 f32 = 98.7 MB
  float* buf1  = wsf;                                          // x2 fp32; later xl bf16 (alias)
  float* stats = wsf + 4194304;                                // 256 f
  __hip_bfloat16* W4a  = (__hip_bfloat16*)(wsf + 4194560);     // 110,592 bf16
  __hip_bfloat16* W4b  = W4a + 110592;
  __hip_bfloat16* Wlr  = (__hip_bfloat16*)(wsf + 4305152);     // 16,384 bf16
  __hip_bfloat16* Wdbc = (__hip_bfloat16*)(wsf + 4313344);     // 20,480 bf16
  __hip_bfloat16* oWp  = (__hip_bfloat16*)(wsf + 4323584);     // 8,192 bf16
  __hip_bfloat16* xpad = (__hip_bfloat16*)(wsf + 4327680);     // 5,030,912 bf16 (conv phase)
  __hip_bfloat16* lnx  = xpad;                                 // alias (post-conv)
  __hip_bfloat16* Lbuf = (__hip_bfloat16*)(wsf + 6843136);     // 8,388,608 bf16
  __hip_bfloat16* Gbuf = (__hip_bfloat16*)(wsf + 11037440);    // 8,388,608 bf16
  __hip_bfloat16* dbc  = (__hip_bfloat16*)(wsf + 15231744);    // 10,485,760 bf16
  __hip_bfloat16* Ybuf = (__hip_bfloat16*)(wsf + 20474624);    // 8,388,608 bf16
  __hip_bfloat16* xl   = (__hip_bfloat16*)buf1;                // alias (x2 dead after ln_k)

  zero_k<<<2457, 256, 0, stream>>>((uint4*)xpad, 628864);
  wpack_k<<<432, 256, 0, stream>>>(cr1w, W4a);
  wpack_k<<<432, 256, 0, stream>>>(cr2w, W4b);
  mamba_wprep_k<<<176, 256, 0, stream>>>(left_w, rw, dw, bpw, cpw, ow, Wlr, Wdbc, oWp);

  dim3 cgrid(256, 1, 2);
  // conv-res block 1
  pack_k<<<2048, 256, 0, stream>>>(x, xpad);
  conv_mfma_k<<<cgrid, 256, 0, stream>>>(xpad, W4a, out);
  inorm_stats_k<<<128, 256, 0, stream>>>(out, stats);
  inorm_apply_k<<<16384, 256, 0, stream>>>(x, out, stats, buf1);
  // conv-res block 2
  pack_k<<<2048, 256, 0, stream>>>(buf1, xpad);
  conv_mfma_k<<<cgrid, 256, 0, stream>>>(xpad, W4b, out);
  inorm_stats_k<<<128, 256, 0, stream>>>(out, stats);
  inorm_apply_k<<<16384, 256, 0, stream>>>(buf1, out, stats, buf1);

  // mamba: axis-independent parts once
  ln_k<<<2048, 256, 0, stream>>>(buf1, ln_w, ln_b, lnx);       // buf1 (x2) dead after this
  gemm_lr_k<<<1024, 256, 0, stream>>>(lnx, Wlr, Lbuf, Gbuf);

  // per-axis: conv1d -> dbc GEMM -> scan -> out GEMM (accumulate into d_out)
  const int sh[3] = {10, 5, 0};
  for (int axis = 0; axis < 3; axis++){
    conv1d_silu_k<<<4096, 256, 0, stream>>>(Lbuf, c1dw, c1db, xl, sh[axis]);
    gemm_dbc_k<<<1024, 256, 0, stream>>>(xl, Wdbc, db, dbc);
    scan_k<<<2048, 128, 0, stream>>>(dbc, xl, Gbuf, alog, pnw, pnb, Ybuf, axis);
    gemm_out_k<<<1024, 256, 0, stream>>>(Ybuf, oWp, axw, out, axis, axis == 0 ? 1 : 0);
  }
  final_k<<<16384, 256, 0, stream>>>(x, rsc, out);
}